// Round 1
// baseline (499.590 us; speedup 1.0000x reference)
//
#include <hip/hip_runtime.h>
#include <hip/hip_bf16.h>

// Per-edge dot product: out[e] = sum_k h[src[e]][k] * h[dst[e]][k], D=128.
// 32 lanes cooperate on one edge: lane i loads float4 #i of both rows
// (32*4 = 128 floats), computes a 4-wide partial dot, then width-32
// shuffle-reduces. Rows are 512 B and 512 B-aligned -> one fully coalesced
// burst per row.

__global__ __launch_bounds__(256) void edge_dot_kernel(
    const float4* __restrict__ h4,   // h reinterpreted as [N_NODES][32] float4
    const int*    __restrict__ src,
    const int*    __restrict__ dst,
    float*        __restrict__ out,
    int n_edges)
{
    const int tid  = blockIdx.x * blockDim.x + threadIdx.x;
    const int edge = tid >> 5;        // 32 lanes per edge
    const int lane = tid & 31;
    if (edge >= n_edges) return;

    const int s = src[edge];
    const int d = dst[edge];

    const float4 a = h4[(size_t)s * 32 + lane];
    const float4 b = h4[(size_t)d * 32 + lane];

    float p = a.x * b.x + a.y * b.y + a.z * b.z + a.w * b.w;

    // Reduce across the 32 lanes owning this edge (stays within half-wave).
    #pragma unroll
    for (int off = 16; off > 0; off >>= 1)
        p += __shfl_down(p, off, 32);

    if (lane == 0)
        out[edge] = p;
}

extern "C" void kernel_launch(void* const* d_in, const int* in_sizes, int n_in,
                              void* d_out, int out_size, void* d_ws, size_t ws_size,
                              hipStream_t stream)
{
    const float* h   = (const float*)d_in[0];
    const int*   src = (const int*)d_in[1];
    const int*   dst = (const int*)d_in[2];
    float*       out = (float*)d_out;

    const int n_edges = in_sizes[1];          // 3.2M

    const int threads = 256;                  // 8 edges per block
    const int edges_per_block = threads / 32;
    const int blocks = (n_edges + edges_per_block - 1) / edges_per_block;

    edge_dot_kernel<<<blocks, threads, 0, stream>>>(
        (const float4*)h, src, dst, out, n_edges);
}